// Round 1
// baseline (208.174 us; speedup 1.0000x reference)
//
#include <hip/hip_runtime.h>

#define NTOK 65536
#define DIN 128
#define DH 256
#define DOUT 128
#define NEXP 8
#define TAUF 5.0f

typedef __attribute__((ext_vector_type(8))) short short8;
typedef __attribute__((ext_vector_type(4))) float f32x4;

// ---- workspace layout (bytes) ----
#define OFF_CNT0 0
#define OFF_CNT1 64
#define OFF_WG   1024                      // 128*8 f32 = 4096
#define OFF_BG   6144                      // 8 f32
#define OFF_W1F  8192                      // 8*128*256 bf16 = 524288
#define OFF_W2F  (OFF_W1F + NEXP*DIN*DH*2) // 8*256*128 bf16 = 524288
#define OFF_L0   (OFF_W2F + NEXP*DH*DOUT*2)
#define OFF_L1   (OFF_L0 + NTOK*NEXP*8)
// end = OFF_L1 + NTOK*NEXP*8  ~= 9.45 MB

__device__ __forceinline__ unsigned short f2bf(float f) {
  union { float f; unsigned u; } v; v.f = f;
  unsigned u = v.u;
  return (unsigned short)((u + 0x7FFFu + ((u >> 16) & 1u)) >> 16);
}

// ---- kernel 1: fuse gate matrices: Wg = Wp @ E_emb, bg = bp @ E_emb ----
__global__ void k_prep_gate(const float* __restrict__ Wp, const float* __restrict__ bp,
                            const float* __restrict__ Ee, float* __restrict__ Wg,
                            float* __restrict__ bg) {
  int t = threadIdx.x;
  for (int i = 0; i < 4; i++) {
    int o = t + i * 256;          // o = k*8 + e, 1024 total
    int k = o >> 3, e = o & 7;
    float s = 0.f;
    for (int l = 0; l < 64; l++) s += Wp[k * 64 + l] * Ee[l * 8 + e];
    Wg[o] = s;
  }
  if (t < 8) {
    float s = 0.f;
    for (int l = 0; l < 64; l++) s += bp[l] * Ee[l * 8 + t];
    bg[t] = s;
  }
}

// ---- kernel 2: convert W1/W2 to bf16 in B-frag-linear layout [kk][n][k%32] ----
// blocks 0..31: W1 (e = b/4, kk = b%4); blocks 32..95: W2 (e = (b-32)/8, kk = (b-32)%8)
__global__ void k_conv_w(const float* __restrict__ W1, const float* __restrict__ W2,
                         unsigned short* __restrict__ W1F, unsigned short* __restrict__ W2F) {
  __shared__ float sl[32 * 257];
  int b = blockIdx.x, t = threadIdx.x;
  const float* src; unsigned short* dst;
  int stride, iters, cshift;
  if (b < 32) {
    int e = b >> 2, kk = b & 3;
    src = W1 + e * (DIN * DH) + kk * 32 * DH;
    dst = W1F + e * (DIN * DH) + kk * (32 * DH);
    stride = 257; iters = 32; cshift = 8;           // 32 x 256 slab
  } else {
    int bb = b - 32;
    int e = bb >> 3, kk = bb & 7;
    src = W2 + e * (DH * DOUT) + kk * 32 * DOUT;
    dst = W2F + e * (DH * DOUT) + kk * (32 * DOUT);
    stride = 129; iters = 16; cshift = 7;           // 32 x 128 slab
  }
  int ncols_m1 = (1 << cshift) - 1;
  for (int i = 0; i < iters; i++) {
    int idx = t + i * 256;
    int r = idx >> cshift, c = idx & ncols_m1;      // coalesced read along cols
    sl[r * stride + c] = src[idx];
  }
  __syncthreads();
  for (int i = 0; i < iters; i++) {
    int o = t + i * 256;                            // o = n*32 + c
    int n = o >> 5, cc = o & 31;
    dst[o] = f2bf(sl[cc * stride + n]);             // coalesced bf16 write
  }
}

// ---- kernel 3: gate (logits, sigmoid, top-2, routing lists, p_open) ----
__global__ void __launch_bounds__(256) k_gate(
    const float* __restrict__ x, const float* __restrict__ Wg, const float* __restrict__ bg,
    float* __restrict__ pout,
    int* __restrict__ cnt0, int* __restrict__ cnt1,
    uint2* __restrict__ l0, uint2* __restrict__ l1) {
  __shared__ float xl[64 * 129];
  __shared__ float pr[256 * 9];
  __shared__ float wgl[DIN * 8];
  __shared__ float bgl[8];
  __shared__ int lc0[8], lc1[8], lb0[8], lb1[8];
  int t = threadIdx.x, b = blockIdx.x;
  int tok0 = b * 64;
  for (int i = 0; i < 4; i++) wgl[t + i * 256] = Wg[t + i * 256];
  if (t < 8) { bgl[t] = bg[t]; lc0[t] = 0; lc1[t] = 0; }
  for (int i = 0; i < 32; i++) {
    int idx = t + i * 256;
    int r = idx >> 7, c = idx & 127;
    xl[r * 129 + c] = x[(tok0 + r) * DIN + c];      // coalesced
  }
  __syncthreads();
  {
    int tok = t & 63, seg = t >> 6;
    float acc0 = 0, acc1 = 0, acc2 = 0, acc3 = 0, acc4 = 0, acc5 = 0, acc6 = 0, acc7 = 0;
    int k0 = seg * 32;
    for (int k = k0; k < k0 + 32; k++) {
      float xv = xl[tok * 129 + k];                 // conflict-free (stride 129)
      float4 wa = *(const float4*)&wgl[k * 8];      // broadcast
      float4 wb = *(const float4*)&wgl[k * 8 + 4];
      acc0 += xv * wa.x; acc1 += xv * wa.y; acc2 += xv * wa.z; acc3 += xv * wa.w;
      acc4 += xv * wb.x; acc5 += xv * wb.y; acc6 += xv * wb.z; acc7 += xv * wb.w;
    }
    float* p = &pr[t * 9];
    p[0]=acc0; p[1]=acc1; p[2]=acc2; p[3]=acc3; p[4]=acc4; p[5]=acc5; p[6]=acc6; p[7]=acc7;
  }
  __syncthreads();
  int i0 = 0, i1 = 0; unsigned lp0 = 0, lp1 = 0; float w0 = 0.f, w1 = 0.f;
  if (t < 64) {
    float p[8];
    #pragma unroll
    for (int e = 0; e < 8; e++) {
      float lg = pr[t*9+e] + pr[(64+t)*9+e] + pr[(128+t)*9+e] + pr[(192+t)*9+e] + bgl[e];
      p[e] = 1.f / (1.f + expf(-lg / TAUF));
    }
    float* prow = pout + (unsigned long long)(tok0 + t) * 8;
    #pragma unroll
    for (int e = 0; e < 8; e++) prow[e] = p[e];
    float v0 = -1.f;
    #pragma unroll
    for (int e = 0; e < 8; e++) if (p[e] > v0) { v0 = p[e]; i0 = e; }
    float v1 = -1.f;
    #pragma unroll
    for (int e = 0; e < 8; e++) if (e != i0 && p[e] > v1) { v1 = p[e]; i1 = e; }
    float s = v0 + v1 + 1e-10f;
    w0 = v0 / s; w1 = v1 / s;
    lp0 = (unsigned)atomicAdd(&lc0[i0], 1);
    lp1 = (unsigned)atomicAdd(&lc1[i1], 1);
  }
  __syncthreads();
  if (t < 8) { lb0[t] = atomicAdd(&cnt0[t], lc0[t]); lb1[t] = atomicAdd(&cnt1[t], lc1[t]); }
  __syncthreads();
  if (t < 64) {
    union { float f; unsigned u; } uw;
    uw.f = w0; l0[i0 * NTOK + lb0[i0] + (int)lp0] = make_uint2((unsigned)(tok0 + t), uw.u);
    uw.f = w1; l1[i1 * NTOK + lb1[i1] + (int)lp1] = make_uint2((unsigned)(tok0 + t), uw.u);
  }
}

// ---- kernel 4: expert compute (routed, bf16 MFMA, 64-token tiles) ----
// accumulate==0: plain store (slot-0 list covers every token exactly once)
// accumulate==1: plain load+add (slot-1 list covers every token exactly once)
__global__ void __launch_bounds__(256) k_expert(
    const float* __restrict__ x,
    const unsigned short* __restrict__ W1F, const unsigned short* __restrict__ W2F,
    const float* __restrict__ b1, const float* __restrict__ b2,
    const int* __restrict__ cnts, const uint2* __restrict__ lst,
    float* __restrict__ out, int accumulate) {
  __shared__ int toks[64];
  __shared__ float wts[64];
  __shared__ unsigned short xs[64 * 136];   // 64 x 128 bf16, pad 8 -> b128 reads 2-way free
  __shared__ unsigned short hs[64 * 264];   // 64 x 256 bf16, pad 8
  int b = blockIdx.x;
  int e = b & 7, tile = b >> 3;
  int cnt = cnts[e];
  int start = tile * 64;
  if (start >= cnt) return;
  int cvalid = min(64, cnt - start);
  int t = threadIdx.x;
  if (t < 64) {
    if (t < cvalid) {
      uint2 en = lst[e * NTOK + start + t];
      toks[t] = (int)en.x;
      union { unsigned u; float f; } uw; uw.u = en.y;
      wts[t] = uw.f;
    } else { toks[t] = 0; wts[t] = 0.f; }   // safe dummy; stores masked below
  }
  __syncthreads();
  { // gather x rows -> bf16 LDS
    int r = t >> 2, qq = t & 3;
    const float* xr = x + (long long)toks[r] * DIN + qq * 32;
    unsigned short* dr = xs + r * 136 + qq * 32;
    #pragma unroll
    for (int i = 0; i < 8; i++) {
      float4 f = *(const float4*)(xr + i * 4);
      unsigned u0 = (unsigned)f2bf(f.x) | ((unsigned)f2bf(f.y) << 16);
      unsigned u1 = (unsigned)f2bf(f.z) | ((unsigned)f2bf(f.w) << 16);
      *(uint2*)(dr + i * 4) = make_uint2(u0, u1);
    }
  }
  __syncthreads();
  int lane = t & 63, w = t >> 6;
  int q = lane >> 4, n16 = lane & 15;
  const unsigned short* W1e = W1F + e * (DIN * DH);
  const unsigned short* W2e = W2F + e * (DH * DOUT);
  const f32x4 vzero = {0.f, 0.f, 0.f, 0.f};
  // ---- GEMM1: H = relu(X @ W1 + b1); wave w -> hidden cols [w*64, w*64+64) ----
  {
    float b1v[4];
    #pragma unroll
    for (int nt = 0; nt < 4; nt++) b1v[nt] = b1[e * DH + w * 64 + nt * 16 + n16];
    f32x4 acc[4][4];
    #pragma unroll
    for (int mt = 0; mt < 4; mt++)
      #pragma unroll
      for (int nt = 0; nt < 4; nt++) acc[mt][nt] = vzero;
    #pragma unroll
    for (int kk = 0; kk < 4; kk++) {
      short8 a[4];
      #pragma unroll
      for (int mt = 0; mt < 4; mt++)
        a[mt] = *(const short8*)(xs + (mt * 16 + n16) * 136 + kk * 32 + q * 8);
      #pragma unroll
      for (int nt = 0; nt < 4; nt++) {
        short8 bb = *(const short8*)(W1e + kk * (DH * 32) + (w * 64 + nt * 16 + n16) * 32 + q * 8);
        #pragma unroll
        for (int mt = 0; mt < 4; mt++)
          acc[mt][nt] = __builtin_amdgcn_mfma_f32_16x16x32_bf16(a[mt], bb, acc[mt][nt], 0, 0, 0);
      }
    }
    #pragma unroll
    for (int mt = 0; mt < 4; mt++)
      #pragma unroll
      for (int nt = 0; nt < 4; nt++)
        #pragma unroll
        for (int r = 0; r < 4; r++) {
          float v = fmaxf(acc[mt][nt][r] + b1v[nt], 0.f);
          hs[(mt * 16 + q * 4 + r) * 264 + w * 64 + nt * 16 + n16] = f2bf(v);
        }
  }
  __syncthreads();
  // ---- GEMM2: O = H @ W2 + b2; wave w -> rows [(w&1)*32,+32), cols [(w>>1)*64,+64) ----
  {
    int mb = (w & 1) * 2;
    int cb = (w >> 1) * 64;
    float b2v[4];
    #pragma unroll
    for (int nt = 0; nt < 4; nt++) b2v[nt] = b2[e * DOUT + cb + nt * 16 + n16];
    f32x4 acc2[2][4];
    #pragma unroll
    for (int m = 0; m < 2; m++)
      #pragma unroll
      for (int nt = 0; nt < 4; nt++) acc2[m][nt] = vzero;
    #pragma unroll
    for (int kk = 0; kk < 8; kk++) {
      short8 a[2];
      #pragma unroll
      for (int m = 0; m < 2; m++)
        a[m] = *(const short8*)(hs + ((mb + m) * 16 + n16) * 264 + kk * 32 + q * 8);
      #pragma unroll
      for (int nt = 0; nt < 4; nt++) {
        short8 bb = *(const short8*)(W2e + kk * (DOUT * 32) + (cb + nt * 16 + n16) * 32 + q * 8);
        #pragma unroll
        for (int m = 0; m < 2; m++)
          acc2[m][nt] = __builtin_amdgcn_mfma_f32_16x16x32_bf16(a[m], bb, acc2[m][nt], 0, 0, 0);
      }
    }
    #pragma unroll
    for (int m = 0; m < 2; m++)
      #pragma unroll
      for (int r = 0; r < 4; r++) {
        int row = (mb + m) * 16 + q * 4 + r;
        if (row < cvalid) {
          float wv = wts[row];
          float* orow = out + (long long)toks[row] * DOUT + cb + n16;
          #pragma unroll
          for (int nt = 0; nt < 4; nt++) {
            float v = (acc2[m][nt][r] + b2v[nt]) * wv;
            if (accumulate) orow[nt * 16] += v;
            else            orow[nt * 16] = v;
          }
        }
      }
  }
}

extern "C" void kernel_launch(void* const* d_in, const int* in_sizes, int n_in,
                              void* d_out, int out_size, void* d_ws, size_t ws_size,
                              hipStream_t stream) {
  const float* x  = (const float*)d_in[0];
  const float* Wp = (const float*)d_in[1];
  const float* bp = (const float*)d_in[2];
  const float* Ee = (const float*)d_in[3];
  const float* W1 = (const float*)d_in[4];
  const float* b1 = (const float*)d_in[5];
  const float* W2 = (const float*)d_in[6];
  const float* b2 = (const float*)d_in[7];
  float* out = (float*)d_out;
  char* ws = (char*)d_ws;
  int* cnt0 = (int*)(ws + OFF_CNT0);
  int* cnt1 = (int*)(ws + OFF_CNT1);
  float* Wg = (float*)(ws + OFF_WG);
  float* bg = (float*)(ws + OFF_BG);
  unsigned short* W1F = (unsigned short*)(ws + OFF_W1F);
  unsigned short* W2F = (unsigned short*)(ws + OFF_W2F);
  uint2* l0 = (uint2*)(ws + OFF_L0);
  uint2* l1 = (uint2*)(ws + OFF_L1);
  float* pout = out + (unsigned long long)NTOK * DOUT + 1;

  hipMemsetAsync(ws, 0, 128, stream);                                   // cnt0 + cnt1
  hipMemsetAsync(out + (unsigned long long)NTOK * DOUT, 0, 4, stream);  // scalar aux output
  k_prep_gate<<<1, 256, 0, stream>>>(Wp, bp, Ee, Wg, bg);
  k_conv_w<<<96, 256, 0, stream>>>(W1, W2, W1F, W2F);
  k_gate<<<NTOK / 64, 256, 0, stream>>>(x, Wg, bg, pout, cnt0, cnt1, l0, l1);
  k_expert<<<8192, 256, 0, stream>>>(x, W1F, W2F, b1, b2, cnt0, l0, out, 0);
  k_expert<<<8192, 256, 0, stream>>>(x, W1F, W2F, b1, b2, cnt1, l1, out, 1);
}

// Round 2
// 175.442 us; speedup vs baseline: 1.1866x; 1.1866x over previous
//
#include <hip/hip_runtime.h>

#define NTOK 65536
#define DIN 128
#define DH 256
#define DOUT 128
#define NEXP 8
#define NPAIR 28
#define CAP 16384
#define TAUF 5.0f

typedef __attribute__((ext_vector_type(8))) short short8;
typedef __attribute__((ext_vector_type(4))) float f32x4;

// ---- workspace layout (bytes) ----
#define OFF_CNT 0                              // 28 ints, pad to 128
#define OFF_WG  128                            // 1024 f32
#define OFF_BG  4352                           // 8 f32
#define OFF_W1F 4608                           // 8*128*256 bf16 = 524288
#define OFF_W2F (OFF_W1F + NEXP*DIN*DH*2)      // 524288
#define OFF_L   (OFF_W2F + NEXP*DH*DOUT*2)     // 28*16384*16 = 7340032
// total ~8.4 MB (< 9.45 MB used successfully in round 1)

__device__ __forceinline__ unsigned short f2bf(float f) {
  union { float f; unsigned u; } v; v.f = f;
  unsigned u = v.u;
  return (unsigned short)((u + 0x7FFFu + ((u >> 16) & 1u)) >> 16);
}

// ---- kernel 1: weight conversion (blocks 0..95) + gate-matrix fuse (block 96) ----
__global__ void k_prep_conv(const float* __restrict__ W1, const float* __restrict__ W2,
                            unsigned short* __restrict__ W1F, unsigned short* __restrict__ W2F,
                            const float* __restrict__ Wp, const float* __restrict__ bp,
                            const float* __restrict__ Ee, float* __restrict__ Wg,
                            float* __restrict__ bg) {
  __shared__ float sl[32 * 257];
  int b = blockIdx.x, t = threadIdx.x;
  if (b == 96) {  // gate fuse: Wg = Wp @ E_emb, bg = bp @ E_emb
    for (int i = 0; i < 4; i++) {
      int o = t + i * 256;
      int k = o >> 3, e = o & 7;
      float s = 0.f;
      for (int l = 0; l < 64; l++) s += Wp[k * 64 + l] * Ee[l * 8 + e];
      Wg[o] = s;
    }
    if (t < 8) {
      float s = 0.f;
      for (int l = 0; l < 64; l++) s += bp[l] * Ee[l * 8 + t];
      bg[t] = s;
    }
    return;
  }
  const float* src; unsigned short* dst;
  int stride, iters, cshift;
  if (b < 32) {
    int e = b >> 2, kk = b & 3;
    src = W1 + e * (DIN * DH) + kk * 32 * DH;
    dst = W1F + e * (DIN * DH) + kk * (32 * DH);
    stride = 257; iters = 32; cshift = 8;           // 32 x 256 slab
  } else {
    int bb = b - 32;
    int e = bb >> 3, kk = bb & 7;
    src = W2 + e * (DH * DOUT) + kk * 32 * DOUT;
    dst = W2F + e * (DH * DOUT) + kk * (32 * DOUT);
    stride = 129; iters = 16; cshift = 7;           // 32 x 128 slab
  }
  int ncols_m1 = (1 << cshift) - 1;
  for (int i = 0; i < iters; i++) {
    int idx = t + i * 256;
    int r = idx >> cshift, c = idx & ncols_m1;
    sl[r * stride + c] = src[idx];
  }
  __syncthreads();
  for (int i = 0; i < iters; i++) {
    int o = t + i * 256;                            // o = n*32 + c (B-frag linear)
    int n = o >> 5, cc = o & 31;
    dst[o] = f2bf(sl[cc * stride + n]);
  }
}

// ---- kernel 2: gate (logits, sigmoid, top-2, pair-bucket routing, p_open) ----
__global__ void __launch_bounds__(256) k_gate(
    const float* __restrict__ x, const float* __restrict__ Wg, const float* __restrict__ bg,
    float* __restrict__ pout, int* __restrict__ cnt, uint4* __restrict__ lst) {
  __shared__ float xl[64 * 132];
  __shared__ float pr[256 * 9];
  __shared__ float wgl[1024];
  __shared__ float bgl[8];
  __shared__ int lc[NPAIR], lb[NPAIR];
  int t = threadIdx.x, b = blockIdx.x;
  int tok0 = b * 64;
  for (int i = 0; i < 4; i++) wgl[t + i * 256] = Wg[t + i * 256];
  if (t < 8) bgl[t] = bg[t];
  if (t < NPAIR) lc[t] = 0;
  const float4* x4 = (const float4*)(x + (size_t)tok0 * DIN);
  for (int i = 0; i < 8; i++) {
    int idx = t + i * 256;
    int r = idx >> 5, c4 = idx & 31;
    *(float4*)&xl[r * 132 + c4 * 4] = x4[r * 32 + c4];   // coalesced 16B, aligned
  }
  __syncthreads();
  {
    int tok = t & 63, seg = t >> 6;
    float a0=0,a1=0,a2=0,a3=0,a4=0,a5=0,a6=0,a7=0;
    int k0 = seg * 32;
    for (int k = k0; k < k0 + 32; k++) {
      float xv = xl[tok * 132 + k];
      float4 wa = *(const float4*)&wgl[k * 8];
      float4 wb = *(const float4*)&wgl[k * 8 + 4];
      a0 += xv * wa.x; a1 += xv * wa.y; a2 += xv * wa.z; a3 += xv * wa.w;
      a4 += xv * wb.x; a5 += xv * wb.y; a6 += xv * wb.z; a7 += xv * wb.w;
    }
    float* p = &pr[t * 9];
    p[0]=a0; p[1]=a1; p[2]=a2; p[3]=a3; p[4]=a4; p[5]=a5; p[6]=a6; p[7]=a7;
  }
  __syncthreads();
  int pid = 0; unsigned pos = 0; unsigned wAb = 0, wBb = 0;
  if (t < 64) {
    float p[8];
    #pragma unroll
    for (int e = 0; e < 8; e++) {
      float lg = pr[t*9+e] + pr[(64+t)*9+e] + pr[(128+t)*9+e] + pr[(192+t)*9+e] + bgl[e];
      p[e] = 1.f / (1.f + expf(-lg / TAUF));
    }
    float* prow = pout + (size_t)(tok0 + t) * 8;
    #pragma unroll
    for (int e = 0; e < 8; e++) prow[e] = p[e];
    int i0 = 0; float v0 = -1.f;
    #pragma unroll
    for (int e = 0; e < 8; e++) if (p[e] > v0) { v0 = p[e]; i0 = e; }
    int i1 = -1; float v1 = -1.f;
    #pragma unroll
    for (int e = 0; e < 8; e++) if (e != i0 && p[e] > v1) { v1 = p[e]; i1 = e; }
    float s = v0 + v1 + 1e-10f;
    float w0 = v0 / s, w1 = v1 / s;
    int eA, eB; float wA, wB;
    if (i0 < i1) { eA = i0; eB = i1; wA = w0; wB = w1; }
    else         { eA = i1; eB = i0; wA = w1; wB = w0; }
    pid = 7 * eA - (eA * (eA - 1)) / 2 + (eB - eA - 1);   // 28 unordered pairs
    union { float f; unsigned u; } ua, ub; ua.f = wA; ub.f = wB;
    wAb = ua.u; wBb = ub.u;
    pos = (unsigned)atomicAdd(&lc[pid], 1);
  }
  __syncthreads();
  if (t < NPAIR) lb[t] = atomicAdd(&cnt[t], lc[t]);
  __syncthreads();
  if (t < 64) {
    int gi = lb[pid] + (int)pos;
    if (gi < CAP) lst[pid * CAP + gi] = make_uint4((unsigned)(tok0 + t), wAb, wBb, 0u);
  }
}

// ---- kernel 3: paired expert compute (both experts of a token in one block) ----
__global__ void __launch_bounds__(256, 3) k_expert(
    const float* __restrict__ x,
    const unsigned short* __restrict__ W1F, const unsigned short* __restrict__ W2F,
    const float* __restrict__ b1, const float* __restrict__ b2,
    const int* __restrict__ cnt, const uint4* __restrict__ lst,
    float* __restrict__ out) {
  __shared__ int cs[NPAIR];
  __shared__ int toks[64];
  __shared__ float wAs[64], wBs[64];
  __shared__ unsigned short xs[64 * 136];   // 17408 B
  __shared__ unsigned short hs[64 * 264];   // 33792 B   (total ~52 KB -> 3 blocks/CU)
  int t = threadIdx.x;
  if (t < NPAIR) cs[t] = cnt[t];
  __syncthreads();
  // map flat block id -> (bucket, tile)
  int gid = blockIdx.x;
  int bsel = -1, tIn = 0, cum = 0;
  #pragma unroll
  for (int bb = 0; bb < NPAIR; bb++) {
    int c = cs[bb]; c = (c > CAP) ? CAP : c;
    int tb = (c + 63) >> 6;
    if (bsel < 0 && gid < cum + tb) { bsel = bb; tIn = gid - cum; }
    cum += tb;
  }
  if (bsel < 0) return;
  int eA = 0, eB = 1;
  { int r = bsel;
    #pragma unroll
    for (int a = 0; a < 7; a++) { int span = 7 - a; if (r < span) { eA = a; eB = a + 1 + r; break; } r -= span; } }
  int cntb = cs[bsel]; cntb = (cntb > CAP) ? CAP : cntb;
  int start = tIn * 64;
  int cvalid = min(64, cntb - start);
  if (t < 64) {
    if (t < cvalid) {
      uint4 en = lst[bsel * CAP + start + t];
      toks[t] = (int)en.x;
      union { unsigned u; float f; } ua, ub; ua.u = en.y; ub.u = en.z;
      wAs[t] = ua.f; wBs[t] = ub.f;
    } else { toks[t] = 0; wAs[t] = 0.f; wBs[t] = 0.f; }
  }
  __syncthreads();
  // gather x rows -> bf16 LDS (full-row coalesced: 32 lanes cover one 512B row)
  for (int i = 0; i < 8; i++) {
    int idx = i * 256 + t;
    int r = idx >> 5, c4 = idx & 31;
    float4 f = *(const float4*)(x + (size_t)toks[r] * DIN + c4 * 4);
    unsigned u0 = (unsigned)f2bf(f.x) | ((unsigned)f2bf(f.y) << 16);
    unsigned u1 = (unsigned)f2bf(f.z) | ((unsigned)f2bf(f.w) << 16);
    *(uint2*)(xs + r * 136 + c4 * 4) = make_uint2(u0, u1);
  }
  __syncthreads();
  int lane = t & 63, w = t >> 6;
  int q = lane >> 4, n16 = lane & 15;
  const f32x4 vz = {0.f, 0.f, 0.f, 0.f};
  for (int pass = 0; pass < 2; pass++) {
    int e = pass ? eB : eA;
    if (pass) __syncthreads();   // all waves done reading hs from pass 0
    // ---- GEMM1: H = relu(X @ W1[e] + b1[e]); wave w -> hidden cols [w*64, w*64+64) ----
    {
      const unsigned short* W1e = W1F + e * (DIN * DH);
      const unsigned short* Bp = W1e + (w * 64 + n16) * 32 + q * 8;
      float b1v[4];
      #pragma unroll
      for (int nt = 0; nt < 4; nt++) b1v[nt] = b1[e * DH + w * 64 + nt * 16 + n16];
      f32x4 acc[4][4];
      #pragma unroll
      for (int mt = 0; mt < 4; mt++)
        #pragma unroll
        for (int nt = 0; nt < 4; nt++) acc[mt][nt] = vz;
      short8 bcur[4], bnxt[4];
      #pragma unroll
      for (int nt = 0; nt < 4; nt++) bcur[nt] = *(const short8*)(Bp + nt * 512);
      #pragma unroll
      for (int kk = 0; kk < 4; kk++) {
        if (kk < 3) {
          #pragma unroll
          for (int nt = 0; nt < 4; nt++) bnxt[nt] = *(const short8*)(Bp + (kk + 1) * 8192 + nt * 512);
        }
        short8 a[4];
        #pragma unroll
        for (int mt = 0; mt < 4; mt++)
          a[mt] = *(const short8*)(xs + (mt * 16 + n16) * 136 + kk * 32 + q * 8);
        #pragma unroll
        for (int nt = 0; nt < 4; nt++)
          #pragma unroll
          for (int mt = 0; mt < 4; mt++)
            acc[mt][nt] = __builtin_amdgcn_mfma_f32_16x16x32_bf16(a[mt], bcur[nt], acc[mt][nt], 0, 0, 0);
        #pragma unroll
        for (int nt = 0; nt < 4; nt++) bcur[nt] = bnxt[nt];
      }
      #pragma unroll
      for (int mt = 0; mt < 4; mt++)
        #pragma unroll
        for (int nt = 0; nt < 4; nt++)
          #pragma unroll
          for (int r = 0; r < 4; r++) {
            float v = fmaxf(acc[mt][nt][r] + b1v[nt], 0.f);
            hs[(mt * 16 + q * 4 + r) * 264 + w * 64 + nt * 16 + n16] = f2bf(v);
          }
    }
    __syncthreads();
    // ---- GEMM2: O_e = H @ W2[e] + b2[e]; wave -> rows [(w&1)*32,+32), cols [(w>>1)*64,+64) ----
    {
      const unsigned short* W2e = W2F + e * (DH * DOUT);
      int mb = (w & 1) * 2;
      int cb = (w >> 1) * 64;
      const unsigned short* Bp = W2e + (cb + n16) * 32 + q * 8;
      float b2v[4];
      #pragma unroll
      for (int nt = 0; nt < 4; nt++) b2v[nt] = b2[e * DOUT + cb + nt * 16 + n16];
      f32x4 acc2[2][4];
      #pragma unroll
      for (int m = 0; m < 2; m++)
        #pragma unroll
        for (int nt = 0; nt < 4; nt++) acc2[m][nt] = vz;
      short8 bcur[8], bnxt[8];
      #pragma unroll
      for (int i = 0; i < 8; i++)
        bcur[i] = *(const short8*)(Bp + (i >> 2) * 4096 + (i & 3) * 512);
      #pragma unroll
      for (int kc = 0; kc < 4; kc++) {
        if (kc < 3) {
          #pragma unroll
          for (int i = 0; i < 8; i++)
            bnxt[i] = *(const short8*)(Bp + (kc * 2 + 2 + (i >> 2)) * 4096 + (i & 3) * 512);
        }
        #pragma unroll
        for (int kk2 = 0; kk2 < 2; kk2++) {
          int kk = kc * 2 + kk2;
          short8 a[2];
          #pragma unroll
          for (int m = 0; m < 2; m++)
            a[m] = *(const short8*)(hs + ((mb + m) * 16 + n16) * 264 + kk * 32 + q * 8);
          #pragma unroll
          for (int nt = 0; nt < 4; nt++)
            #pragma unroll
            for (int m = 0; m < 2; m++)
              acc2[m][nt] = __builtin_amdgcn_mfma_f32_16x16x32_bf16(a[m], bcur[kk2 * 4 + nt], acc2[m][nt], 0, 0, 0);
        }
        #pragma unroll
        for (int i = 0; i < 8; i++) bcur[i] = bnxt[i];
      }
      const float* wsel = pass ? wBs : wAs;
      #pragma unroll
      for (int m = 0; m < 2; m++)
        #pragma unroll
        for (int r = 0; r < 4; r++) {
          int row = (mb + m) * 16 + q * 4 + r;
          if (row < cvalid) {
            float wv = wsel[row];
            float* orow = out + (size_t)toks[row] * DOUT + cb + n16;
            #pragma unroll
            for (int nt = 0; nt < 4; nt++) {
              float v = (acc2[m][nt][r] + b2v[nt]) * wv;
              if (pass) orow[nt * 16] += v;   // same lane wrote this addr in pass 0 -> L2 hit, coherent
              else      orow[nt * 16] = v;
            }
          }
        }
    }
  }
}

extern "C" void kernel_launch(void* const* d_in, const int* in_sizes, int n_in,
                              void* d_out, int out_size, void* d_ws, size_t ws_size,
                              hipStream_t stream) {
  const float* x  = (const float*)d_in[0];
  const float* Wp = (const float*)d_in[1];
  const float* bp = (const float*)d_in[2];
  const float* Ee = (const float*)d_in[3];
  const float* W1 = (const float*)d_in[4];
  const float* b1 = (const float*)d_in[5];
  const float* W2 = (const float*)d_in[6];
  const float* b2 = (const float*)d_in[7];
  float* out = (float*)d_out;
  char* ws = (char*)d_ws;
  int* cnt = (int*)(ws + OFF_CNT);
  float* Wg = (float*)(ws + OFF_WG);
  float* bg = (float*)(ws + OFF_BG);
  unsigned short* W1F = (unsigned short*)(ws + OFF_W1F);
  unsigned short* W2F = (unsigned short*)(ws + OFF_W2F);
  uint4* lst = (uint4*)(ws + OFF_L);
  float* pout = out + (size_t)NTOK * DOUT + 1;

  hipMemsetAsync(ws, 0, 128, stream);                              // pair counters
  hipMemsetAsync(out + (size_t)NTOK * DOUT, 0, 4, stream);         // scalar aux output
  k_prep_conv<<<97, 256, 0, stream>>>(W1, W2, W1F, W2F, Wp, bp, Ee, Wg, bg);
  k_gate<<<NTOK / 64, 256, 0, stream>>>(x, Wg, bg, pout, cnt, lst);
  k_expert<<<1056, 256, 0, stream>>>(x, W1F, W2F, b1, b2, cnt, lst, out);
}